// Round 8
// baseline (1314.524 us; speedup 1.0000x reference)
//
#include <hip/hip_runtime.h>

#define NB_ 5   // N_BASIS
#define MD_ 5   // MAX_DELAY
#define AGENT __HIP_MEMORY_SCOPE_AGENT

// ---------------------------------------------------------------------------
// Sense-reversing grid barrier, agent scope, hand-rolled (NOT cg::sync).
// cnt/gen zeroed by the launcher's memset each replay; mygen is a t0 register.
// ---------------------------------------------------------------------------
__device__ __forceinline__ void grid_barrier(int* cnt, int* gen, int nblk, int& mygen)
{
    __syncthreads();
    if (threadIdx.x == 0) {
        ++mygen;
        int old = __hip_atomic_fetch_add(cnt, 1, __ATOMIC_ACQ_REL, AGENT);
        if (old == nblk - 1) {
            __hip_atomic_store(cnt, 0, __ATOMIC_RELAXED, AGENT);
            __hip_atomic_store(gen, mygen, __ATOMIC_RELEASE, AGENT);
        } else {
            while (__hip_atomic_load(gen, __ATOMIC_ACQUIRE, AGENT) < mygen)
                __builtin_amdgcn_s_sleep(1);
        }
    }
    __syncthreads();
}

// ---------------------------------------------------------------------------
// One persistent cooperative kernel runs all T steps.
//  - thread tid < N owns neuron tid; ALL state + params in registers
//  - spikes bit-packed in zbits rows (row u+MD = step u), written via
//    agent-scope atomic stores (bypass non-coherent per-XCD L2)
//  - recurrent edge path: lazy push-model, gated by window spike count
//    (never taken for this input; fully correct if spikes occur)
//  - 1 custom barrier per step (+1 inside the spike branch)
// ---------------------------------------------------------------------------
__global__ __launch_bounds__(1024, 1) void v1_persist(
    const float* __restrict__ weights,
    const float* __restrict__ edge_basis,
    const float* __restrict__ ext_input,
    const float* __restrict__ decay_g,
    const float* __restrict__ cf_g,
    const float* __restrict__ g_g,
    const float* __restrict__ vth_g,
    const float* __restrict__ vrst_g,
    const float* __restrict__ nrm_g,
    const float* __restrict__ tref_g,
    const float* __restrict__ ek_g,      // (N,2)
    const float* __restrict__ am_g,      // (N,2)
    const float* __restrict__ sd_g,      // n5
    const float* __restrict__ pi_g,      // n5
    const int*   __restrict__ pre_idx,
    const int*   __restrict__ post_idx,
    float*       __restrict__ out,       // (T,N)
    int*   bar_cnt, int* bar_gen,
    int*   scnt,                          // (T+MD)
    float* i_rec,                         // n5, pre-zeroed
    unsigned int* zbits,                  // (T+MD)*words32, head pre-zeroed
    int N, int E, int T, int words32, int nblk)
{
    __shared__ int ss[MD_];
    const int tid = blockIdx.x * blockDim.x + threadIdx.x;
    const int nth = gridDim.x * blockDim.x;
    const int n5  = N * NB_;
    const int words64 = words32 >> 1;
    unsigned long long* zb64 = (unsigned long long*)zbits;
    int mygen = 0;

    // ---------------- register-resident state + parameters ------------------
    const int  n   = tid;
    const bool has = (n < N);
    float dec = 0.f, cf = 0.f, gg = 0.f, vth = 0.f, vrst = 0.f, nrm = 0.f, tref = 0.f;
    float ek0 = 0.f, ek1 = 0.f, am0 = 0.f, am1 = 0.f;
    float sdv[NB_], piv[NB_], p[NB_];
    #pragma unroll
    for (int k = 0; k < NB_; ++k) { sdv[k] = 0.f; piv[k] = 0.f; p[k] = 0.f; }
    float v = 0.f, r = 0.f, a0 = 0.f, a1 = 0.f, pz = 0.f;
    if (has) {
        dec = decay_g[n]; cf = cf_g[n]; gg = g_g[n];
        vth = vth_g[n]; vrst = vrst_g[n]; nrm = nrm_g[n]; tref = tref_g[n];
        ek0 = ek_g[2 * n]; ek1 = ek_g[2 * n + 1];
        am0 = am_g[2 * n]; am1 = am_g[2 * n + 1];
        #pragma unroll
        for (int k = 0; k < NB_; ++k) {
            sdv[k] = sd_g[(size_t)n * NB_ + k];
            piv[k] = pi_g[(size_t)n * NB_ + k];
        }
        v = vrst;
    }

    // prefetch x for step 0
    float xv[NB_] = {0.f, 0.f, 0.f, 0.f, 0.f};
    if (has) {
        const float* xp = ext_input + (size_t)n * NB_;
        #pragma unroll
        for (int k = 0; k < NB_; ++k) xv[k] = xp[k];
    }

    for (int t = 0; t < T; ++t) {
        // ---- window spike count (rows t..t+4; agent loads bypass stale L2) --
        if (threadIdx.x < MD_)
            ss[threadIdx.x] = __hip_atomic_load(&scnt[t + threadIdx.x],
                                                __ATOMIC_RELAXED, AGENT);
        __syncthreads();
        int scw = ss[0] + ss[1] + ss[2] + ss[3] + ss[4];   // grid-uniform

        // ---- lazy recurrent path (never taken for this input) --------------
        float ir0 = 0.f, ir1 = 0.f, ir2 = 0.f, ir3 = 0.f, ir4 = 0.f;
        if (scw > 0) {
            for (int e = tid; e < E; e += nth) {
                int pre = pre_idx[e];
                int d  = pre / N;
                int nn = pre - d * N;
                int row = t + (MD_ - 1 - d);           // holds z of step t-1-d
                unsigned w = __hip_atomic_load(
                    &zbits[(size_t)row * words32 + (nn >> 5)],
                    __ATOMIC_RELAXED, AGENT);
                if ((w >> (nn & 31)) & 1u) {
                    float wt = weights[e];
                    const float* bs = edge_basis + (size_t)e * NB_;
                    float* ir = i_rec + (size_t)post_idx[e] * NB_;
                    atomicAdd(ir + 0, wt * bs[0]);
                    atomicAdd(ir + 1, wt * bs[1]);
                    atomicAdd(ir + 2, wt * bs[2]);
                    atomicAdd(ir + 3, wt * bs[3]);
                    atomicAdd(ir + 4, wt * bs[4]);
                }
            }
            grid_barrier(bar_cnt, bar_gen, nblk, mygen);
            if (has) {
                float* ir = i_rec + (size_t)n * NB_;
                ir0 = __hip_atomic_load(ir + 0, __ATOMIC_RELAXED, AGENT);
                ir1 = __hip_atomic_load(ir + 1, __ATOMIC_RELAXED, AGENT);
                ir2 = __hip_atomic_load(ir + 2, __ATOMIC_RELAXED, AGENT);
                ir3 = __hip_atomic_load(ir + 3, __ATOMIC_RELAXED, AGENT);
                ir4 = __hip_atomic_load(ir + 4, __ATOMIC_RELAXED, AGENT);
                __hip_atomic_store(ir + 0, 0.0f, __ATOMIC_RELAXED, AGENT);
                __hip_atomic_store(ir + 1, 0.0f, __ATOMIC_RELAXED, AGENT);
                __hip_atomic_store(ir + 2, 0.0f, __ATOMIC_RELAXED, AGENT);
                __hip_atomic_store(ir + 3, 0.0f, __ATOMIC_RELAXED, AGENT);
                __hip_atomic_store(ir + 4, 0.0f, __ATOMIC_RELAXED, AGENT);
            }
        }

        // ---- neuron update (registers; exact reference op order) -----------
        float z = 0.0f;
        if (has) {
            float ic = 0.0f, pv;
            pv = p[0] * sdv[0] + (ir0 + xv[0]) * piv[0]; p[0] = pv; ic += pv;
            pv = p[1] * sdv[1] + (ir1 + xv[1]) * piv[1]; p[1] = pv; ic += pv;
            pv = p[2] * sdv[2] + (ir2 + xv[2]) * piv[2]; p[2] = pv; ic += pv;
            pv = p[3] * sdv[3] + (ir3 + xv[3]) * piv[3]; p[3] = pv; ic += pv;
            pv = p[4] * sdv[4] + (ir4 + xv[4]) * piv[4]; p[4] = pv; ic += pv;

            a0 = ek0 * a0 + pz * am0;
            a1 = ek1 * a1 + pz * am1;
            float c1 = ic + (a0 + a1) + gg;
            float nv = dec * v + cf * c1;
            if (pz > 0.5f) nv = vrst;

            float vsc = (nv - vth) / nrm;
            z = (vsc > 0.0f) ? 1.0f : 0.0f;
            if (r > 0.0f) z = 0.0f;
            r = fmaxf(r + z * tref - 1.0f, 0.0f);   // DT = 1.0
            v = nv;
            pz = z;
            out[(size_t)t * N + n] = z;
        }

        // ---- publish spikes of step t (row t+MD), agent-scope --------------
        unsigned long long m = __ballot(z != 0.0f);
        int wv = tid >> 6;
        if ((threadIdx.x & 63) == 0 && (wv << 6) < N) {
            __hip_atomic_store(zb64 + (size_t)(t + MD_) * words64 + wv, m,
                               __ATOMIC_RELAXED, AGENT);
            if (m) __hip_atomic_fetch_add(&scnt[t + MD_], (int)__popcll(m),
                                          __ATOMIC_RELAXED, AGENT);
        }

        // ---- prefetch x for step t+1 (hides HBM latency under the spin) ----
        if (has && t + 1 < T) {
            const float* xp = ext_input + (size_t)(t + 1) * n5 + (size_t)n * NB_;
            #pragma unroll
            for (int k = 0; k < NB_; ++k) xv[k] = xp[k];
        }

        if (t + 1 < T)
            grid_barrier(bar_cnt, bar_gen, nblk, mygen);
    }
}

// ---------------------------------------------------------------------------
// Launcher: one memset + one cooperative launch.
// ---------------------------------------------------------------------------
extern "C" void kernel_launch(void* const* d_in, const int* in_sizes, int n_in,
                              void* d_out, int out_size, void* d_ws, size_t ws_size,
                              hipStream_t stream)
{
    const float* weights        = (const float*)d_in[0];
    const float* edge_basis     = (const float*)d_in[1];
    const float* ext_input      = (const float*)d_in[2];
    const float* decay          = (const float*)d_in[3];
    const float* current_factor = (const float*)d_in[4];
    const float* gathered_g     = (const float*)d_in[5];
    const float* v_th           = (const float*)d_in[6];
    const float* v_reset        = (const float*)d_in[7];
    const float* normalizer     = (const float*)d_in[8];
    const float* t_ref          = (const float*)d_in[9];
    const float* exp_dt_k       = (const float*)d_in[10];
    const float* asc_amps       = (const float*)d_in[11];
    const float* syn_decay      = (const float*)d_in[12];
    const float* psc_initial    = (const float*)d_in[13];
    const int*   pre_idx        = (const int*)d_in[14];
    const int*   post_idx       = (const int*)d_in[15];

    const int E  = in_sizes[0];
    const int N  = in_sizes[3];
    const int n5 = N * NB_;
    const int T  = in_sizes[2] / n5;          // B = 1

    const int words64 = (N + 63) / 64;        // 782
    const int words32 = words64 * 2;          // 1564

    float* out = (float*)d_out;

    // ---- workspace layout (zero group is one contiguous memset) ------------
    char* wsb = (char*)d_ws;
    size_t o = 0;
    int*   bar_cnt = (int*)(wsb + o);  o += 8;      // cnt, pad
    int*   bar_gen = (int*)(wsb + o);  o += 8;      // gen, pad
    int*   scnt    = (int*)(wsb + o);  o += (size_t)(T + MD_) * 4;
    o = (o + 15) & ~(size_t)15;
    float* i_rec   = (float*)(wsb + o); o += (size_t)n5 * 4;
    o = (o + 15) & ~(size_t)15;
    unsigned int* zbits = (unsigned int*)(wsb + o);
    size_t zero_bytes = o + (size_t)MD_ * words32 * 4;   // through zbits head
    o += (size_t)(T + MD_) * words32 * 4;

    hipMemsetAsync(d_ws, 0, zero_bytes, stream);

    const int BLK  = 1024;
    const int nblk = (N + BLK - 1) / BLK;     // 49 blocks (all co-resident)

    void* args[] = {
        (void*)&weights, (void*)&edge_basis, (void*)&ext_input,
        (void*)&decay, (void*)&current_factor, (void*)&gathered_g,
        (void*)&v_th, (void*)&v_reset, (void*)&normalizer, (void*)&t_ref,
        (void*)&exp_dt_k, (void*)&asc_amps, (void*)&syn_decay, (void*)&psc_initial,
        (void*)&pre_idx, (void*)&post_idx,
        (void*)&out,
        (void*)&bar_cnt, (void*)&bar_gen, (void*)&scnt, (void*)&i_rec, (void*)&zbits,
        (void*)&N, (void*)&E, (void*)&T, (void*)&words32, (void*)&nblk
    };
    hipLaunchCooperativeKernel((void*)v1_persist, dim3(nblk), dim3(BLK), args,
                               0, stream);
}